// Round 1
// baseline (304.515 us; speedup 1.0000x reference)
//
#include <hip/hip_runtime.h>
#include <stdint.h>

typedef unsigned short u16;
typedef __bf16 bf16x8 __attribute__((ext_vector_type(8)));
typedef float f32x4 __attribute__((ext_vector_type(4)));

typedef __attribute__((address_space(3))) void lds_void;
typedef const __attribute__((address_space(1))) void gbl_void;
#define GLD_LDS16(g, l) __builtin_amdgcn_global_load_lds((gbl_void*)(g), (lds_void*)(l), 16, 0, 0)

// Relaxed barrier (old 128^2 pipeline, still used by k_gemm_o)
#define BAR_RELAX() asm volatile("s_waitcnt vmcnt(4)\n\ts_barrier" ::: "memory")
#define BAR_FULL()  asm volatile("s_waitcnt vmcnt(0)\n\ts_barrier" ::: "memory")
// 8-phase primitives: raw barrier (NO waitcnt drain) + counted vmcnt waits
#define BAR()   asm volatile("s_barrier" ::: "memory")
#define VMW(n)  asm volatile("s_waitcnt vmcnt(" #n ")" ::: "memory")

__device__ __forceinline__ u16 f2bf(float f) {
  unsigned u = __float_as_uint(f);
  u += 0x7fffu + ((u >> 16) & 1u);   // RNE
  return (u16)(u >> 16);
}

// pack bf16(a) | bf16(b)<<16 with round-half-up via v_perm_b32
__device__ __forceinline__ unsigned pk2bf(float a, float b) {
  unsigned au = __float_as_uint(a) + 0x8000u;
  unsigned bu = __float_as_uint(b) + 0x8000u;
  return __builtin_amdgcn_perm(bu, au, 0x07060302u);
}

// ---- fused prepass: all fp32 -> bf16 conversions in one launch ----
__global__ void k_convert_all(const float* __restrict__ inq, const float* __restrict__ r_q,
                              const float* __restrict__ inkv, const float* __restrict__ r_kv,
                              const float* __restrict__ w_q, const float* __restrict__ w_kv,
                              const float* __restrict__ w_o,
                              u16* __restrict__ Xq, u16* __restrict__ Xkv,
                              u16* __restrict__ Wq, u16* __restrict__ Wkv,
                              u16* __restrict__ Wo) {
  int blk = blockIdx.x;
  const float* src; const float* r = nullptr; u16* dst; int base;
  if (blk < 8192)       { src = inq;  r = r_q;  dst = Xq;  base = 0; }
  else if (blk < 16384) { src = inkv; r = r_kv; dst = Xkv; base = 8192; }
  else if (blk < 17408) { src = w_q;  dst = Wq;  base = 16384; }
  else if (blk < 19456) { src = w_kv; dst = Wkv; base = 17408; }
  else                  { src = w_o;  dst = Wo;  base = 19456; }
  int i4 = ((blk - base) * 256 + threadIdx.x) * 4;
  float4 xv = *(const float4*)(src + i4);
  if (r) {
    int rb = ((i4 >> 10) & 7) * 1024 + (i4 & 1023);
    float4 rv = *(const float4*)(r + rb);
    xv.x *= rv.x; xv.y *= rv.y; xv.z *= rv.z; xv.w *= rv.w;
  }
  unsigned long long pk = (unsigned long long)pk2bf(xv.x, xv.y)
      | ((unsigned long long)pk2bf(xv.z, xv.w) << 32);
  *(unsigned long long*)(dst + i4) = pk;
}

// =====================================================================
// 8-phase 256x256 GEMM (BK=64, 8 waves, 512 threads), C = A * B^T.
// K fixed at 1024 (16 K-tiles, 8 main iterations of 2 K-tiles each).
// LDS: A,B double-buffered 256x64 bf16 tiles = 128 KiB -> 1 block/CU.
// Stage units per K-tile (16KB = 2 global_load_lds per thread each):
//   B0 = B rows 0-127, B1 = rows 128-255,
//   Aq01 = A rows {0-63,128-191}, Aq23 = A rows {64-127,192-255}
// Issue schedule per iteration (tiles t=2i, t+1):
//   p1: Aq23(t+1)->As1  p2: B0(t+2)->Bs0  p3: B1(t+2)->Bs0  p4: Aq01(t+2)->As0
//   p5: Aq23(t+2)->As0  p6: B0(t+3)->Bs1  p7: B1(t+3)->Bs1  p8: Aq01(t+3)->As1
// vmcnt(6) before the trailing barrier of p4 guarantees tile t+1 staged
// (its newest unit was issued at p1); at p8 it guarantees tile t+2
// (newest unit at p5). Each stage targets regions whose last reader's
// phase barrier has already passed (B read only at p1/p5; A quadrant q
// read at phase q). Last iteration drains with vmcnt(0) at p4.
// =====================================================================
template <class F0, class F1, class F2, class F3>
__device__ __forceinline__ void four_phases(const u16* AsT, const u16* BsT,
                                            int rowA, int rowB, int bof0, int bof1,
                                            f32x4 (&acc)[8][4],
                                            F0 st0, F1 st1, F2 st2, F3 st3, bool drain) {
  bf16x8 bfr[4][2];
#pragma unroll
  for (int nt = 0; nt < 4; ++nt) {
    bfr[nt][0] = *(const bf16x8*)(BsT + rowB + (nt << 10) + bof0);
    bfr[nt][1] = *(const bf16x8*)(BsT + rowB + (nt << 10) + bof1);
  }
#pragma unroll
  for (int q = 0; q < 4; ++q) {
    bf16x8 af[2][2];
#pragma unroll
    for (int j = 0; j < 2; ++j) {
      af[j][0] = *(const bf16x8*)(AsT + rowA + ((2 * q + j) << 10) + bof0);
      af[j][1] = *(const bf16x8*)(AsT + rowA + ((2 * q + j) << 10) + bof1);
    }
    if (q == 0) st0(); else if (q == 1) st1(); else if (q == 2) st2(); else st3();
    BAR();
    __builtin_amdgcn_s_setprio(1);
#pragma unroll
    for (int j = 0; j < 2; ++j)
#pragma unroll
      for (int nt = 0; nt < 4; ++nt) {
        acc[2 * q + j][nt] = __builtin_amdgcn_mfma_f32_16x16x32_bf16(af[j][0], bfr[nt][0], acc[2 * q + j][nt], 0, 0, 0);
        acc[2 * q + j][nt] = __builtin_amdgcn_mfma_f32_16x16x32_bf16(af[j][1], bfr[nt][1], acc[2 * q + j][nt], 0, 0, 0);
      }
    __builtin_amdgcn_s_setprio(0);
    if (q == 3) { if (drain) VMW(0); else VMW(6); }
    BAR();
  }
}

// MODE 0: bf16 out, C = (acc * s[(m&7)*N+n] + bias[n]) * postscale
// MODE 2: kv mode — K cols -> compact kbuf(t,head,d); V cols -> vt[head][d][t]
template <int MODE>
__device__ __forceinline__ void gemm256(const u16* __restrict__ Amat, const u16* __restrict__ Bmat,
                                        void* __restrict__ Cout, const float* __restrict__ s,
                                        const float* __restrict__ bias, int N, float postscale,
                                        int bx, int by,
                                        u16* As0, u16* As1, u16* Bs0, u16* Bs1,
                                        int tid, u16* __restrict__ vt) {
  const int w = tid >> 6, lane = tid & 63;
  const int quad = lane >> 4, l16 = lane & 15;
  const int wm = w & 1, wn = w >> 1;          // 2M x 4N waves, 128x64 out each
  const int m0 = by << 8, n0g = bx << 8;

  // staging: thread covers row (row0 + w*8 + lane/8), 16B block lane&7.
  // LDS dest linear; SOURCE col-block pre-swizzled with (row&7) so that
  // ds_read block (ks*4+quad)^(row&7) recovers the linear k-block.
  const int thr_row = (w << 3) + (lane >> 3);
  const int sblk = (lane & 7) ^ ((lane >> 3) & 7);

  auto STG = [&](u16* lds, const u16* mat, int rowbase, int k0, int row0) {
    GLD_LDS16(mat + (size_t)(rowbase + row0 + thr_row) * 1024 + k0 + (sblk << 3),
              lds + ((row0 + (w << 3)) << 6));
  };

  const int sw = l16 & 7;
  const int bof0 = (quad ^ sw) << 3;          // ks=0 swizzled block byte/2 offset
  const int bof1 = ((4 | quad) ^ sw) << 3;    // ks=1
  const int rowA = ((wm << 7) + l16) << 6;
  const int rowB = ((wn << 6) + l16) << 6;

  f32x4 acc[8][4] = {};

  // prologue: tile0 {Aq01,Aq23,B0,B1} + tile1 {B0,B1,Aq01}; tile1's Aq23 at iter0.p1
  STG(As0, Amat, m0, 0, 0);    STG(As0, Amat, m0, 0, 128);
  STG(As0, Amat, m0, 0, 64);   STG(As0, Amat, m0, 0, 192);
  STG(Bs0, Bmat, n0g, 0, 0);   STG(Bs0, Bmat, n0g, 0, 64);
  STG(Bs0, Bmat, n0g, 0, 128); STG(Bs0, Bmat, n0g, 0, 192);
  STG(Bs1, Bmat, n0g, 64, 0);  STG(Bs1, Bmat, n0g, 64, 64);
  STG(Bs1, Bmat, n0g, 64, 128);STG(Bs1, Bmat, n0g, 64, 192);
  STG(As1, Amat, m0, 64, 0);   STG(As1, Amat, m0, 64, 128);
  VMW(6);   // oldest 8 = tile0 complete; tile1's 6 may remain in flight
  BAR();

#pragma unroll 1
  for (int i = 0; i < 8; ++i) {
    const int k0 = i << 7;
    const bool more = i < 7;
    four_phases(As0, Bs0, rowA, rowB, bof0, bof1, acc,
        [&]{ STG(As1, Amat, m0, k0 + 64, 64);  STG(As1, Amat, m0, k0 + 64, 192); },
        [&]{ if (more) { STG(Bs0, Bmat, n0g, k0 + 128, 0);   STG(Bs0, Bmat, n0g, k0 + 128, 64); } },
        [&]{ if (more) { STG(Bs0, Bmat, n0g, k0 + 128, 128); STG(Bs0, Bmat, n0g, k0 + 128, 192); } },
        [&]{ if (more) { STG(As0, Amat, m0, k0 + 128, 0);    STG(As0, Amat, m0, k0 + 128, 128); } },
        !more);
    four_phases(As1, Bs1, rowA, rowB, bof0, bof1, acc,
        [&]{ if (more) { STG(As0, Amat, m0, k0 + 128, 64);   STG(As0, Amat, m0, k0 + 128, 192); } },
        [&]{ if (more) { STG(Bs1, Bmat, n0g, k0 + 192, 0);   STG(Bs1, Bmat, n0g, k0 + 192, 64); } },
        [&]{ if (more) { STG(Bs1, Bmat, n0g, k0 + 192, 128); STG(Bs1, Bmat, n0g, k0 + 192, 192); } },
        [&]{ if (more) { STG(As1, Amat, m0, k0 + 192, 0);    STG(As1, Amat, m0, k0 + 192, 128); } },
        false);
  }

  // epilogue
#pragma unroll
  for (int mt = 0; mt < 8; ++mt)
#pragma unroll
    for (int nt = 0; nt < 4; ++nt) {
      const int n = n0g + (wn << 6) + (nt << 4) + l16;
#pragma unroll
      for (int rg = 0; rg < 4; ++rg) {
        const int m = m0 + (wm << 7) + (mt << 4) + (quad << 2) + rg;
        float v = acc[mt][nt][rg];
        if (MODE == 0) {
          v = (v * s[(m & 7) * N + n] + bias[n]) * postscale;
          ((u16*)Cout)[(size_t)m * N + n] = f2bf(v);
        } else {
          v = v * s[(m & 7) * N + n] + bias[n];
          const int b = m & 7, tk = m >> 3;
          const int head = (b << 4) + (n >> 7);
          const int dloc = n & 63;
          if (((n >> 6) & 1) == 0)
            ((u16*)Cout)[((size_t)(tk * 128 + head) << 6) + dloc] = f2bf(v);
          else
            vt[((size_t)((head << 6) + dloc) << 10) + tk] = f2bf(v);
        }
      }
    }
}

// fused q + kv projection GEMMs, 8-phase 256^2 tiles, XCD-banded (384 blocks).
__global__ __launch_bounds__(512, 2) void k_gemm_qkv(
    const u16* __restrict__ Xq, const u16* __restrict__ Wq,
    u16* __restrict__ qout, const float* __restrict__ s_q,
    const float* __restrict__ b_q, float qscale,
    const u16* __restrict__ Xkv, const u16* __restrict__ Wkv,
    u16* __restrict__ kbuf, const float* __restrict__ s_kv,
    const float* __restrict__ b_kv, u16* __restrict__ vt) {
  __shared__ __align__(16) u16 As[2][16384];
  __shared__ __align__(16) u16 Bs[2][16384];
  const int blk = blockIdx.x;
  const int xcd = blk & 7;
  const int slot = blk >> 3;                 // 0..47
  const int by = xcd * 4 + slot / 12;        // 0..31
  const int cx = slot % 12;                  // 0..3 q, 4..11 kv
  if (cx < 4)
    gemm256<0>(Xq, Wq, qout, s_q, b_q, 1024, qscale, cx, by,
               &As[0][0], &As[1][0], &Bs[0][0], &Bs[1][0], threadIdx.x, nullptr);
  else
    gemm256<2>(Xkv, Wkv, kbuf, s_kv, b_kv, 2048, 1.0f, cx - 4, by,
               &As[0][0], &As[1][0], &Bs[0][0], &Bs[1][0], threadIdx.x, vt);
}

// ---- old GEMM tile body (kept for k_gemm_o): 128x128, BK=32, 3-stage ----
template <int MODE>
__device__ __forceinline__ void gemm_tile(const u16* __restrict__ A, const u16* __restrict__ B,
                                          void* __restrict__ Cout, const float* __restrict__ s,
                                          const float* __restrict__ bias, int N, int K,
                                          float postscale, int bx, int by,
                                          u16* As, u16* Bs, int tid,
                                          u16* __restrict__ vt, int h) {
  const int w = tid >> 6, lane = tid & 63;
  const int quad = lane >> 4, l16 = lane & 15;
  const int n0 = bx * 128, m0 = by * 128;
  const int wm = (w & 1) * 64, wn = (w >> 1) * 64;

  f32x4 acc[4][4] = {};

  int srow[2], scol[2];
#pragma unroll
  for (int i = 0; i < 2; ++i) {
    int p = (w * 2 + i) * 64 + lane;
    int row = p >> 2;
    int cb = (p & 3) ^ ((row >> 1) & 3);
    srow[i] = row; scol[i] = cb * 8;
  }
  int offA[4], offB[4];
#pragma unroll
  for (int t = 0; t < 4; ++t) {
    int ra = wm + t * 16 + l16;
    offA[t] = ra * 32 + ((quad ^ ((ra >> 1) & 3)) * 8);
    int rb = wn + t * 16 + l16;
    offB[t] = rb * 32 + ((quad ^ ((rb >> 1) & 3)) * 8);
  }

#pragma unroll
  for (int st = 0; st < 2; ++st)
#pragma unroll
    for (int i = 0; i < 2; ++i) {
      GLD_LDS16(A + (size_t)(m0 + srow[i]) * K + st * 32 + scol[i],
                As + st * 4096 + (w * 2 + i) * 512);
      GLD_LDS16(B + (size_t)(n0 + srow[i]) * K + st * 32 + scol[i],
                Bs + st * 4096 + (w * 2 + i) * 512);
    }

  int cur = 0, nxt = 2;
#pragma unroll 1
  for (int k0 = 0; k0 < K; k0 += 32) {
    if (k0 + 32 >= K) BAR_FULL(); else BAR_RELAX();

    if (k0 + 64 < K) {
#pragma unroll
      for (int i = 0; i < 2; ++i) {
        GLD_LDS16(A + (size_t)(m0 + srow[i]) * K + (k0 + 64) + scol[i],
                  As + nxt * 4096 + (w * 2 + i) * 512);
        GLD_LDS16(B + (size_t)(n0 + srow[i]) * K + (k0 + 64) + scol[i],
                  Bs + nxt * 4096 + (w * 2 + i) * 512);
      }
    }
    const u16* Ac = As + cur * 4096;
    const u16* Bc = Bs + cur * 4096;
    bf16x8 af[4], bfr[4];
#pragma unroll
    for (int mt = 0; mt < 4; ++mt) af[mt] = *(const bf16x8*)(Ac + offA[mt]);
#pragma unroll
    for (int nt = 0; nt < 4; ++nt) bfr[nt] = *(const bf16x8*)(Bc + offB[nt]);
#pragma unroll
    for (int mt = 0; mt < 4; ++mt)
#pragma unroll
      for (int nt = 0; nt < 4; ++nt)
        acc[mt][nt] = __builtin_amdgcn_mfma_f32_16x16x32_bf16(af[mt], bfr[nt], acc[mt][nt], 0, 0, 0);
    cur = (cur == 2) ? 0 : cur + 1;
    nxt = (nxt == 2) ? 0 : nxt + 1;
  }

#pragma unroll
  for (int mt = 0; mt < 4; ++mt)
#pragma unroll
    for (int nt = 0; nt < 4; ++nt) {
      int n = n0 + wn + nt * 16 + l16;
#pragma unroll
      for (int rg = 0; rg < 4; ++rg) {
        int m = m0 + wm + mt * 16 + quad * 4 + rg;
        float v = acc[mt][nt][rg];
        if (MODE == 0) {
          v = (v * s[(m & 7) * N + n] + bias[n]) * postscale;
          ((u16*)Cout)[(size_t)m * N + n] = f2bf(v);
        } else if (MODE == 1) {
          ((float*)Cout)[(size_t)m * N + n] = v + bias[n];
        } else {
          v = v * s[(m & 7) * N + n] + bias[n];
          int b = m & 7, tk = m >> 3;
          int head = b * 16 + h;
          int dloc = nt * 16 + l16;
          if (wn == 0) {
            ((u16*)Cout)[((size_t)(tk * 128 + head)) * 64 + dloc] = f2bf(v);
          } else {
            vt[((size_t)(head * 64 + dloc)) * 1024 + tk] = f2bf(v);
          }
        }
      }
    }
}

// output projection GEMM (fp32 out), XCD-banded decode (512 blocks).
__global__ void k_gemm_o(const u16* __restrict__ A, const u16* __restrict__ B,
                         float* __restrict__ Cout, const float* __restrict__ bias) {
  __shared__ __align__(16) u16 As[3 * 4096];
  __shared__ __align__(16) u16 Bs[3 * 4096];
  const int blk = blockIdx.x;
  const int xcd = blk & 7;
  const int slot = blk >> 3;            // 0..63
  const int bx = slot % 8;
  const int by = xcd * 8 + slot / 8;
  gemm_tile<1>(A, B, Cout, nullptr, bias, 1024, 1024, 1.0f, bx, by, As, Bs,
               threadIdx.x, nullptr, 0);
}

// ---- flash attention, G=2: 4 waves x 32 q-cols per 128-q block ----
__global__ __launch_bounds__(256, 3) void k_attn(const u16* __restrict__ qb,
                                                 const u16* __restrict__ kb,
                                                 const u16* __restrict__ vtb,
                                                 u16* __restrict__ ctx) {
  __shared__ __align__(16) u16 Ks[2][4096];
  __shared__ __align__(16) u16 Vts[2][4096];
  __shared__ __align__(16) u16 Ps[4][32 * 72];

  const int tid = threadIdx.x;
  const int w = tid >> 6, lane = tid & 63;
  const int quad = lane >> 4, l16 = lane & 15;
  const int n = blockIdx.x & 127;
  const int q0 = (blockIdx.x >> 7) << 7;
  const int qw = q0 + w * 32;

  bf16x8 bq[2][2];
#pragma unroll
  for (int g = 0; g < 2; ++g)
#pragma unroll
    for (int ks = 0; ks < 2; ++ks)
      bq[g][ks] = *(const bf16x8*)(qb + ((size_t)(qw + g * 16 + l16) * 128 + n) * 64 + ks * 32 + quad * 8);

  const bool isK = (w < 2);
  const int wv = w & 1;
  const u16* gbase[4];
  u16* lbase[4];
#pragma unroll
  for (int i = 0; i < 4; ++i) {
    int p = (wv * 4 + i) * 64 + lane;
    int r = p >> 3;
    int scb = ((p & 7) ^ (r & 7)) * 8;
    if (isK) {
      gbase[i] = kb + ((size_t)r * 128 + n) * 64 + scb;
      lbase[i] = &Ks[0][(wv * 4 + i) * 512];
    } else {
      gbase[i] = vtb + ((size_t)n * 64 + r) * 1024 + scb;
      lbase[i] = &Vts[0][(wv * 4 + i) * 512];
    }
  }
  const size_t gstep = isK ? 8192 : 1;
  const int lstep = 4096;

  float l_i[2] = {0.f, 0.f};
  f32x4 accO[2][4] = {};
  u16* myP = Ps[w];

#pragma unroll
  for (int i = 0; i < 4; ++i) GLD_LDS16(gbase[i], lbase[i]);

#pragma unroll 1
  for (int tk0 = 0; tk0 < 1024; tk0 += 64) {
    const int cur = (tk0 >> 6) & 1;
    __syncthreads();
    if (tk0 < 960) {
      size_t goff = (size_t)(tk0 + 64) * gstep;
#pragma unroll
      for (int i = 0; i < 4; ++i)
        GLD_LDS16(gbase[i] + goff, lbase[i] + (cur ^ 1) * lstep);
    }
    const u16* Kc = Ks[cur];
    const u16* Vc = Vts[cur];

    f32x4 accS[2][4] = {};
#pragma unroll
    for (int mt = 0; mt < 4; ++mt) {
      int r = mt * 16 + l16;
#pragma unroll
      for (int ks = 0; ks < 2; ++ks) {
        bf16x8 ak = *(const bf16x8*)(Kc + r * 64 + (((ks * 4 + quad) ^ (r & 7)) << 3));
#pragma unroll
        for (int g = 0; g < 2; ++g)
          accS[g][mt] = __builtin_amdgcn_mfma_f32_16x16x32_bf16(ak, bq[g][ks], accS[g][mt], 0, 0, 0);
      }
    }

#pragma unroll
    for (int g = 0; g < 2; ++g) {
      float pv[16];
      float ss = 0.f;
#pragma unroll
      for (int mt = 0; mt < 4; ++mt)
#pragma unroll
        for (int rg = 0; rg < 4; ++rg) {
          float p = __builtin_amdgcn_exp2f(accS[g][mt][rg]);
          pv[mt * 4 + rg] = p;
          ss += p;
        }
      ss += __shfl_xor(ss, 16);
      ss += __shfl_xor(ss, 32);
      l_i[g] += ss;
      const int prow = (g * 16 + l16) * 72;
#pragma unroll
      for (int mt = 0; mt < 4; ++mt) {
        unsigned long long pk = (unsigned long long)pk2bf(pv[mt * 4 + 0], pv[mt * 4 + 1])
            | ((unsigned long long)pk2bf(pv[mt * 4 + 2], pv[mt * 4 + 3]) << 32);
        *(unsigned long long*)(myP + prow + mt * 16 + quad * 4) = pk;
      }
    }

    bf16x8 bp[2][2];
#pragma unroll
    for (int g = 0; g < 2; ++g)
#pragma unroll
      for (int ks = 0; ks < 2; ++ks)
        bp[g][ks] = *(const bf16x8*)(myP + (g * 16 + l16) * 72 + ks * 32 + quad * 8);
#pragma unroll
    for (int dt = 0; dt < 4; ++dt) {
      int r = dt * 16 + l16;
#pragma unroll
      for (int ks = 0; ks < 2; ++ks) {
        bf16x8 av = *(const bf16x8*)(Vc + r * 64 + (((ks * 4 + quad) ^ (r & 7)) << 3));
#pragma unroll
        for (int g = 0; g < 2; ++g)
          accO[g][dt] = __builtin_amdgcn_mfma_f32_16x16x32_bf16(av, bp[g][ks], accO[g][dt], 0, 0, 0);
      }
    }
  }

#pragma unroll
  for (int g = 0; g < 2; ++g) {
    float inv = 1.f / l_i[g];
    const size_t obase = ((size_t)(qw + g * 16 + l16) * 128 + n) * 64;
#pragma unroll
    for (int dt = 0; dt < 4; ++dt) {
      unsigned long long pk = (unsigned long long)pk2bf(accO[g][dt][0] * inv, accO[g][dt][1] * inv)
          | ((unsigned long long)pk2bf(accO[g][dt][2] * inv, accO[g][dt][3] * inv) << 32);
      *(unsigned long long*)(ctx + obase + dt * 16 + quad * 4) = pk;
    }
  }
}

extern "C" void kernel_launch(void* const* d_in, const int* in_sizes, int n_in,
                              void* d_out, int out_size, void* d_ws, size_t ws_size,
                              hipStream_t stream) {
  const float* inq  = (const float*)d_in[0];
  const float* inkv = (const float*)d_in[1];
  const float* w_q  = (const float*)d_in[2];
  const float* b_q  = (const float*)d_in[3];
  const float* w_kv = (const float*)d_in[4];
  const float* b_kv = (const float*)d_in[5];
  const float* w_o  = (const float*)d_in[6];
  const float* b_o  = (const float*)d_in[7];
  const float* r_q  = (const float*)d_in[8];
  const float* s_q  = (const float*)d_in[9];
  const float* r_kv = (const float*)d_in[10];
  const float* s_kv = (const float*)d_in[11];

  const size_t MEG = 1024 * 1024;
  u16* ws    = (u16*)d_ws;
  u16* Xq    = ws;               // 8M bf16, later reused as ctx
  u16* Xkv   = ws + 8 * MEG;     // 8M bf16
  u16* Wq    = ws + 16 * MEG;    // 1M
  u16* Wkv   = ws + 17 * MEG;    // 2M
  u16* Wo    = ws + 19 * MEG;    // 1M
  u16* qbuf  = ws + 20 * MEG;    // 8M  (t,head,d)
  u16* kbuf  = ws + 28 * MEG;    // 8M  (t,head,d) compact K
  u16* vt    = ws + 36 * MEG;    // 8M  (head,d,t) transposed V
  u16* ctx   = Xq;               // total 44M u16 = 88 MB

  k_convert_all<<<20480, 256, 0, stream>>>(inq, r_q, inkv, r_kv, w_q, w_kv, w_o,
                                           Xq, Xkv, Wq, Wkv, Wo);

  const float QSCALE = 0.125f * 1.44269504088896340736f;  // hd^-0.5 * log2e into q
  k_gemm_qkv<<<384, 512, 0, stream>>>(Xq, Wq, qbuf, s_q, b_q, QSCALE,
                                      Xkv, Wkv, kbuf, s_kv, b_kv, vt);
  k_attn<<<1024, 256, 0, stream>>>(qbuf, kbuf, vt, ctx);
  k_gemm_o<<<512, 256, 0, stream>>>(ctx, Wo, (float*)d_out, b_o);
}